// Round 9
// baseline (127.755 us; speedup 1.0000x reference)
//
#include <hip/hip_runtime.h>

// Tucker reconstruction + gather, bf16 MFMA pipeline (3 dispatches):
//   K01f: [mode-0 v2: A1t[i][c][b] = sum_a f0[i][a]*core[a][b][c], core read
//          ONCE (256 blocks, 16x16 bc-tile, all 40 i, f0 via scalar loads)]
//         + [cvt f1,f2 -> bf16] + [parallel bucket builder, 40 blocks]
//   K2' : A2[i*768+j][c] = sum_b f1[j][b]*A1t[i][c][b]  (only gathered rows)
//   K3  : out[n][k] = sum_c A2[ids[n]][c]*f2[k][c]      (64n x 128k tiles)
// ids < 30522 <= 30720; duplicate/pad rows recompute identical values (benign).
// R7 lesson: serial bucket block ~20us -> 40 parallel blocks. R5 lesson:
// hipLaunchCooperativeKernel silently fails in this harness. R8 lesson: k2 was
// only ~3-4us; the big remaining cost was mode-0's 8x core re-read.

#define A_DIM 40
#define BC 65536   // 256*256
#define C_DIM 256
#define HID 768
#define CAP 320    // bucket capacity (mean 206, +8 sigma)

typedef __attribute__((ext_vector_type(8))) short short8;   // 8 x bf16 (4 VGPR)
typedef __attribute__((ext_vector_type(4))) float floatx4;  // MFMA C/D

#define AS1 __attribute__((address_space(1)))
#define AS3 __attribute__((address_space(3)))

// async 16B global->LDS DMA: per-lane global addr (gather OK), wave-uniform LDS
// base; HW writes lane i at base + i*16.
__device__ __forceinline__ void gl2lds16(const unsigned short* g, unsigned short* l) {
    __builtin_amdgcn_global_load_lds((const AS1 unsigned int*)g, (AS3 unsigned int*)l,
                                     16, 0, 0);
}

__device__ __forceinline__ unsigned short f2bf(float f) {
    unsigned int u = __builtin_bit_cast(unsigned int, f);
    u += 0x7FFFu + ((u >> 16) & 1u);   // round-to-nearest-even
    return (unsigned short)(u >> 16);
}

// ---------------- K01f: mode-0 v2 + cvt + parallel buckets ------------------
// blocks [0,256): mode-0 v2 (tile b0=(bid>>4)*16, c0=(bid&15)*16, all 40 i)
// blocks [256,640): f1/f2 -> bf16 convert
// blocks [640,680): bucket builder, block 640+i owns bucket i
__global__ __launch_bounds__(256) void k01_fused(const float* __restrict__ core,
                                                 const float* __restrict__ f0,
                                                 const float* __restrict__ f1,
                                                 const float* __restrict__ f2,
                                                 const int* __restrict__ ids,
                                                 unsigned short* __restrict__ A1t,
                                                 unsigned short* __restrict__ f1b,
                                                 unsigned short* __restrict__ f2b,
                                                 int* __restrict__ jslot,
                                                 int* __restrict__ tilecnt) {
    const int bid = blockIdx.x;
    const int tid = threadIdx.x;
    if (bid < 256) {
        // ---- mode-0 v2: core element (b0+lb, c0+lc) read once, all 40 i ----
        const int b0 = (bid >> 4) * 16;
        const int c0 = (bid & 15) * 16;
        const int lb = tid >> 4, lc = tid & 15;
        float cv[A_DIM];
        const float* cp = core + (b0 + lb) * 256 + (c0 + lc);
#pragma unroll
        for (int a = 0; a < A_DIM; ++a) cv[a] = cp[a * BC];   // 40 independent loads

        __shared__ unsigned short tt[8][16 * 17];   // 8 i-planes, pitch 17
        const int wlc = tid >> 4, wlb = tid & 15;   // write mapping (c-row, b)
        for (int i0 = 0; i0 < A_DIM; i0 += 8) {
            unsigned short res[8];
#pragma unroll
            for (int ii = 0; ii < 8; ++ii) {
                float s = 0.f;
                const float* f0r = f0 + (i0 + ii) * A_DIM;    // wave-uniform -> s_load
#pragma unroll
                for (int a = 0; a < A_DIM; ++a) s += f0r[a] * cv[a];
                res[ii] = f2bf(s);
            }
            __syncthreads();    // previous round's tt reads done
#pragma unroll
            for (int ii = 0; ii < 8; ++ii) tt[ii][lc * 17 + lb] = res[ii];
            __syncthreads();
#pragma unroll
            for (int ii = 0; ii < 8; ++ii)
                A1t[(size_t)(i0 + ii) * BC + (c0 + wlc) * 256 + b0 + wlb] =
                    tt[ii][wlc * 17 + wlb];
        }
    } else if (bid < 640) {
        const int idx = (bid - 256) * 256 + tid;       // 49152 float4 per matrix
        const float* src;
        unsigned short* dst;
        int off;
        if (idx < 49152) { src = f1; dst = f1b; off = idx; }
        else             { src = f2; dst = f2b; off = idx - 49152; }
        const float4 v = *(const float4*)&src[off * 4];
        const unsigned int lo = (unsigned int)f2bf(v.x) | ((unsigned int)f2bf(v.y) << 16);
        const unsigned int hi = (unsigned int)f2bf(v.z) | ((unsigned int)f2bf(v.w) << 16);
        *(uint2*)&dst[off * 4] = make_uint2(lo, hi);
    } else {
        // ---- parallel bucket builder: block 640+i collects ids in bucket i ----
        const int i = bid - 640;
        __shared__ int cnt;
        if (tid == 0) cnt = 0;
        __syncthreads();
        const unsigned int lo_id = (unsigned int)i * 768u;
        for (int t = tid; t < 8192; t += 256) {
            const unsigned int id = (unsigned int)ids[t];
            const unsigned int d = id - lo_id;
            if (d < 768u) {
                const int s = atomicAdd(&cnt, 1);
                jslot[i * CAP + s] = (int)d;           // j
            }
        }
        __syncthreads();
        const int u = cnt;
        const int tc = (u + 63) >> 6;                  // tiles of 64
        if (tid == 0) tilecnt[i] = tc;
        for (int s = u + tid; s < tc * 64; s += 256) jslot[i * CAP + s] = 0;  // pads
    }
}

// ---------------- K2': gathered-A compact MFMA GEMM (only needed rows) ------
// Per slot-tile (uniform i): A = f1b rows gathered by js[] (M=64 slots, K=256 b),
// B^T = A1t[i] [c][b] (N=64 c-tile). Epilogue scatters to A2[i*768+j][c].
__global__ __launch_bounds__(256) void k2_gemm(const unsigned short* __restrict__ f1b,
                                               const unsigned short* __restrict__ A1t,
                                               const int* __restrict__ jslot,
                                               const int* __restrict__ tilecnt,
                                               unsigned short* __restrict__ A2) {
    const int T = blockIdx.y;          // 0..199
    const int i = T / 5, t = T % 5;
    if (t >= tilecnt[i]) return;       // uniform branch (scalar load)
    const int c0 = blockIdx.x * 64;
    const int slot0 = i * CAP + t * 64;
    const unsigned short* __restrict__ Bsrc = A1t + i * BC;

    __shared__ int js[64];
    __shared__ unsigned short As[64 * 32];
    __shared__ unsigned short Bs[64 * 32];

    const int tid = threadIdx.x;
    if (tid < 64) js[tid] = jslot[slot0 + tid];
    __syncthreads();

    const int lane = tid & 63, wave = tid >> 6;
    const int wm = (wave >> 1) * 32, wn = (wave & 1) * 32;
    const int l16 = lane & 15, q = lane >> 4;

    const int r0 = tid >> 2, o0 = (tid & 3) * 8;     // staging chunk -> (row, 16B slot)
    const size_t ga = (size_t)js[r0] * 256;          // gathered f1b row base
    unsigned short* AsW = &As[wave * 512];
    unsigned short* BsW = &Bs[wave * 512];

    floatx4 acc[2][2];
#pragma unroll
    for (int p = 0; p < 2; ++p)
#pragma unroll
        for (int r = 0; r < 2; ++r) acc[p][r] = (floatx4)0.f;

    for (int kk = 0; kk < C_DIM; kk += 32) {
        gl2lds16(&f1b[ga + kk + o0], AsW);
        gl2lds16(&Bsrc[(c0 + r0) * 256 + kk + o0], BsW);
        __syncthreads();
        short8 af[2], bf[2];
#pragma unroll
        for (int p = 0; p < 2; ++p) af[p] = *(const short8*)&As[(wm + p * 16 + l16) * 32 + q * 8];
#pragma unroll
        for (int r = 0; r < 2; ++r) bf[r] = *(const short8*)&Bs[(wn + r * 16 + l16) * 32 + q * 8];
#pragma unroll
        for (int p = 0; p < 2; ++p)
#pragma unroll
            for (int r = 0; r < 2; ++r)
                acc[p][r] = __builtin_amdgcn_mfma_f32_16x16x32_bf16(af[p], bf[r], acc[p][r], 0, 0, 0);
        __syncthreads();
    }
#pragma unroll
    for (int p = 0; p < 2; ++p)
#pragma unroll
        for (int r = 0; r < 2; ++r)
#pragma unroll
            for (int rr = 0; rr < 4; ++rr) {
                const int jrow = js[wm + p * 16 + q * 4 + rr];   // C: row=(lane>>4)*4+reg
                const int col = c0 + wn + r * 16 + l16;          //    col=lane&15
                A2[(size_t)(i * HID + jrow) * 256 + col] = f2bf(acc[p][r][rr]);
            }
}

// ---------------- K3: gathered MFMA GEMM, 64n x 128k tile, out f32 ----------
// A = gathered A2 rows [n][c] (M=8192,K=256), B^T = f2b [k][c] (N=768)
// 4 waves: wave tile 32m x 64k -> 8 MFMA : 6 frag-reads : 3 DMA per K-iter.
__global__ __launch_bounds__(256) void k3_gemm(const unsigned short* __restrict__ A2,
                                               const unsigned short* __restrict__ f2b,
                                               const int* __restrict__ ids,
                                               float* __restrict__ out) {
    const int n0 = blockIdx.x * 64;
    const int k0 = blockIdx.y * 128;

    __shared__ int ids_s[64];
    __shared__ unsigned short As[64 * 32];    // 4 KB
    __shared__ unsigned short Bs[128 * 32];   // 8 KB

    const int tid = threadIdx.x;
    if (tid < 64) ids_s[tid] = ids[n0 + tid];
    __syncthreads();

    const int lane = tid & 63, wave = tid >> 6;
    const int wm = (wave & 1) * 32;           // m-half
    const int wk = (wave >> 1) * 64;          // k-half
    const int l16 = lane & 15, q = lane >> 4;

    const int r0 = tid >> 2, o0 = (tid & 3) * 8;   // staging chunk -> (row, 16B slot)
    const size_t ga = (size_t)ids_s[r0] * 256;     // gathered A row base
    unsigned short* AsW  = &As[wave * 512];
    unsigned short* BsW0 = &Bs[wave * 512];
    unsigned short* BsW1 = &Bs[2048 + wave * 512];

    floatx4 acc[2][4];
#pragma unroll
    for (int p = 0; p < 2; ++p)
#pragma unroll
        for (int r = 0; r < 4; ++r) acc[p][r] = (floatx4)0.f;

    for (int kk = 0; kk < C_DIM; kk += 32) {
        gl2lds16(&A2[ga + kk + o0], AsW);
        gl2lds16(&f2b[(k0 + r0) * 256 + kk + o0], BsW0);
        gl2lds16(&f2b[(k0 + 64 + r0) * 256 + kk + o0], BsW1);
        __syncthreads();
        short8 af[2], bf[4];
#pragma unroll
        for (int p = 0; p < 2; ++p) af[p] = *(const short8*)&As[(wm + p * 16 + l16) * 32 + q * 8];
#pragma unroll
        for (int r = 0; r < 4; ++r) bf[r] = *(const short8*)&Bs[(wk + r * 16 + l16) * 32 + q * 8];
#pragma unroll
        for (int p = 0; p < 2; ++p)
#pragma unroll
            for (int r = 0; r < 4; ++r)
                acc[p][r] = __builtin_amdgcn_mfma_f32_16x16x32_bf16(af[p], bf[r], acc[p][r], 0, 0, 0);
        __syncthreads();
    }
#pragma unroll
    for (int p = 0; p < 2; ++p)
#pragma unroll
        for (int r = 0; r < 4; ++r)
#pragma unroll
            for (int rr = 0; rr < 4; ++rr) {
                const int row = n0 + wm + p * 16 + q * 4 + rr;   // C: row=(lane>>4)*4+reg
                const int col = k0 + wk + r * 16 + l16;          //    col=lane&15
                out[(size_t)row * HID + col] = acc[p][r][rr];
            }
}

extern "C" void kernel_launch(void* const* d_in, const int* in_sizes, int n_in,
                              void* d_out, int out_size, void* d_ws, size_t ws_size,
                              hipStream_t stream) {
    // inputs: 0=x(unused), 1=ids, 2=core, 3=f0, 4=f1, 5=f2
    const int*   ids  = (const int*)d_in[1];
    const float* core = (const float*)d_in[2];
    const float* f0   = (const float*)d_in[3];
    const float* f1   = (const float*)d_in[4];
    const float* f2   = (const float*)d_in[5];
    float* out = (float*)d_out;

    char* ws = (char*)d_ws;
    unsigned short* A1t   = (unsigned short*)ws;               //  5,242,880 B
    unsigned short* A2    = (unsigned short*)(ws + 5242880);   // 15,728,640 B
    unsigned short* f1b   = (unsigned short*)(ws + 20971520);  //    393,216 B
    unsigned short* f2b   = (unsigned short*)(ws + 21364736);  //    393,216 B
    int*            jslot = (int*)(ws + 21757952);             //     51,200 B (40*320*4)
    int*            tcnt  = (int*)(ws + 21809152);             //        160 B

    k01_fused<<<680, 256, 0, stream>>>(core, f0, f1, f2, ids, A1t, f1b, f2b, jslot, tcnt);
    k2_gemm<<<dim3(4, 200), 256, 0, stream>>>(f1b, A1t, jslot, tcnt, A2);
    k3_gemm<<<dim3(128, 6), 256, 0, stream>>>(A2, f2b, ids, out);
}

// Round 10
// 112.826 us; speedup vs baseline: 1.1323x; 1.1323x over previous
//
#include <hip/hip_runtime.h>

// Tucker reconstruction + gather, bf16 MFMA pipeline (3 dispatches):
//   K01f: [f1,f2 -> bf16 cvt blocks]  +  [fused mode-0 + transpose:
//          A1t[i][c][b] = sum_a f0[i][a]*core[a][b][c], written directly]
//   K2  : A2[(i*768+j)][c] = sum_b f1[j][b]*A1t[i][c][b]   (MFMA bf16, 64x64)
//   K3  : out[n][k] = sum_c A2[ids[n]][c]*f2[k][c]         (MFMA bf16, gathered)
// table row index == i*768+j == A2 row; ids < 30522 <= 30720 so gather is in-range.
// BEST-KNOWN CONFIG (round-6: 114.1 us). Round-9 lesson: 16x16-tile mode-0 with
// 256-KB-stride core loads at 1 wave/SIMD regressed 13 us — core re-reads were
// L2-free all along. Round-7 lesson: serial bucket block costs ~20 us.
// Round-5 lesson: hipLaunchCooperativeKernel silently fails in this harness.

#define A_DIM 40
#define BC 65536   // 256*256
#define C_DIM 256
#define HID 768

typedef __attribute__((ext_vector_type(8))) short short8;   // 8 x bf16 (4 VGPR)
typedef __attribute__((ext_vector_type(4))) float floatx4;  // MFMA C/D

#define AS1 __attribute__((address_space(1)))
#define AS3 __attribute__((address_space(3)))

// async 16B global->LDS DMA: per-lane global addr (gather OK), wave-uniform LDS
// base; HW writes lane i at base + i*16.
__device__ __forceinline__ void gl2lds16(const unsigned short* g, unsigned short* l) {
    __builtin_amdgcn_global_load_lds((const AS1 unsigned int*)g, (AS3 unsigned int*)l,
                                     16, 0, 0);
}

__device__ __forceinline__ unsigned short f2bf(float f) {
    unsigned int u = __builtin_bit_cast(unsigned int, f);
    u += 0x7FFFu + ((u >> 16) & 1u);   // round-to-nearest-even
    return (unsigned short)(u >> 16);
}

// ---------------- K01f: fused cvt + mode-0 + transpose ----------------------
// blocks [0,512): mode-0+transpose. bid: ig=bid>>6 (i0=ig*5), tile=bid&63
//   (b0=(tile>>3)*32, c0=(tile&7)*32). Thread: 2x2 patch, 5 i accumulators.
// blocks [512,896): f1/f2 -> bf16 convert.
__global__ __launch_bounds__(256) void k01_fused(const float* __restrict__ core,
                                                 const float* __restrict__ f0,
                                                 const float* __restrict__ f1,
                                                 const float* __restrict__ f2,
                                                 unsigned short* __restrict__ A1t,
                                                 unsigned short* __restrict__ f1b,
                                                 unsigned short* __restrict__ f2b) {
    const int bid = blockIdx.x;
    const int tid = threadIdx.x;
    if (bid < 512) {
        __shared__ float f0s[200];                     // f0 rows i0..i0+4
        __shared__ unsigned short tt[32 * 34];         // transposed tile [c][b], pitch 34
        const int i0 = (bid >> 6) * 5;
        const int tile = bid & 63;
        const int b0 = (tile >> 3) * 32;
        const int c0 = (tile & 7) * 32;
        if (tid < 200) f0s[tid] = f0[i0 * A_DIM + tid];
        __syncthreads();

        const int pb = (tid >> 4) * 2;                 // local b of 2x2 patch
        const int pc = (tid & 15) * 2;                 // local c
        float acc[5][4];                               // [ii][{b0c0,b0c1,b1c0,b1c1}]
#pragma unroll
        for (int ii = 0; ii < 5; ++ii)
#pragma unroll
            for (int e = 0; e < 4; ++e) acc[ii][e] = 0.f;

        const float* cp0 = core + (b0 + pb) * 256 + (c0 + pc);
        for (int a = 0; a < A_DIM; ++a) {
            const float* cp = cp0 + a * BC;
            const float2 r0 = *(const float2*)cp;          // [pb  ][pc..pc+1]
            const float2 r1 = *(const float2*)(cp + 256);  // [pb+1][pc..pc+1]
#pragma unroll
            for (int ii = 0; ii < 5; ++ii) {
                const float fa = f0s[ii * A_DIM + a];
                acc[ii][0] += fa * r0.x;   // (b=pb,   c=pc)
                acc[ii][1] += fa * r0.y;   // (b=pb,   c=pc+1)
                acc[ii][2] += fa * r1.x;   // (b=pb+1, c=pc)
                acc[ii][3] += fa * r1.y;   // (b=pb+1, c=pc+1)
            }
        }
        const int rc = tid >> 3;                       // read row (c) 0..31
        const int rb4 = (tid & 7) * 4;                 // read col (b) group of 4
#pragma unroll
        for (int ii = 0; ii < 5; ++ii) {
            if (ii) __syncthreads();
            // store transposed: tt[c][b]; short2 along b (contiguous)
            unsigned short e00 = f2bf(acc[ii][0]);     // c=pc,   b=pb
            unsigned short e10 = f2bf(acc[ii][2]);     // c=pc,   b=pb+1
            unsigned short e01 = f2bf(acc[ii][1]);     // c=pc+1, b=pb
            unsigned short e11 = f2bf(acc[ii][3]);     // c=pc+1, b=pb+1
            *(unsigned int*)&tt[pc * 34 + pb]       = (unsigned int)e00 | ((unsigned int)e10 << 16);
            *(unsigned int*)&tt[(pc + 1) * 34 + pb] = (unsigned int)e01 | ((unsigned int)e11 << 16);
            __syncthreads();
            // coalesced write: row c0+rc, 4 shorts along b
            unsigned short o[4];
#pragma unroll
            for (int u = 0; u < 4; ++u) o[u] = tt[rc * 34 + rb4 + u];
            unsigned int lo = (unsigned int)o[0] | ((unsigned int)o[1] << 16);
            unsigned int hi = (unsigned int)o[2] | ((unsigned int)o[3] << 16);
            *(uint2*)&A1t[(size_t)(i0 + ii) * BC + (c0 + rc) * 256 + b0 + rb4] = make_uint2(lo, hi);
        }
    } else {
        const int idx = (bid - 512) * 256 + tid;       // 49152 float4 per matrix
        const float* src;
        unsigned short* dst;
        int off;
        if (idx < 49152) { src = f1; dst = f1b; off = idx; }
        else             { src = f2; dst = f2b; off = idx - 49152; }
        const float4 v = *(const float4*)&src[off * 4];
        const unsigned int lo = (unsigned int)f2bf(v.x) | ((unsigned int)f2bf(v.y) << 16);
        const unsigned int hi = (unsigned int)f2bf(v.z) | ((unsigned int)f2bf(v.w) << 16);
        *(uint2*)&dst[off * 4] = make_uint2(lo, hi);
    }
}

// ---------------- K2: batched MFMA GEMM, 64x64 tile, BK=32, DMA staging -----
// A = f1b [j][b] (M=768,K=256), B^T = A1t[i] [c][b] (N=256,K=256), C = A2 bf16
// LDS tiles packed [row][32] (64B/row); chunk tid -> row tid>>2, 16B slot tid&3.
__global__ __launch_bounds__(256) void k2_gemm(const unsigned short* __restrict__ f1b,
                                               const unsigned short* __restrict__ A1t,
                                               unsigned short* __restrict__ A2) {
    const int i  = blockIdx.z;
    const int j0 = blockIdx.x * 64;
    const int c0 = blockIdx.y * 64;
    const unsigned short* __restrict__ Bsrc = A1t + i * BC;

    __shared__ unsigned short As[64 * 32];
    __shared__ unsigned short Bs[64 * 32];

    const int tid = threadIdx.x;
    const int lane = tid & 63, wave = tid >> 6;
    const int wm = (wave >> 1) * 32, wn = (wave & 1) * 32;
    const int l16 = lane & 15, q = lane >> 4;

    const int r0 = tid >> 2, o0 = (tid & 3) * 8;     // staging chunk -> (row, 16B slot)
    unsigned short* AsW = &As[wave * 512];           // wave covers chunks wave*64..+63
    unsigned short* BsW = &Bs[wave * 512];

    floatx4 acc[2][2];
#pragma unroll
    for (int p = 0; p < 2; ++p)
#pragma unroll
        for (int r = 0; r < 2; ++r) acc[p][r] = (floatx4)0.f;

    for (int kk = 0; kk < C_DIM; kk += 32) {
        gl2lds16(&f1b[(j0 + r0) * 256 + kk + o0], AsW);
        gl2lds16(&Bsrc[(c0 + r0) * 256 + kk + o0], BsW);
        __syncthreads();
        short8 af[2], bf[2];
#pragma unroll
        for (int p = 0; p < 2; ++p) af[p] = *(const short8*)&As[(wm + p * 16 + l16) * 32 + q * 8];
#pragma unroll
        for (int r = 0; r < 2; ++r) bf[r] = *(const short8*)&Bs[(wn + r * 16 + l16) * 32 + q * 8];
#pragma unroll
        for (int p = 0; p < 2; ++p)
#pragma unroll
            for (int r = 0; r < 2; ++r)
                acc[p][r] = __builtin_amdgcn_mfma_f32_16x16x32_bf16(af[p], bf[r], acc[p][r], 0, 0, 0);
        __syncthreads();
    }
    unsigned short* __restrict__ Cout = A2 + (size_t)i * HID * C_DIM;
#pragma unroll
    for (int p = 0; p < 2; ++p)
#pragma unroll
        for (int r = 0; r < 2; ++r)
#pragma unroll
            for (int rr = 0; rr < 4; ++rr) {
                const int row = j0 + wm + p * 16 + q * 4 + rr;   // C: row=(lane>>4)*4+reg
                const int col = c0 + wn + r * 16 + l16;          //    col=lane&15
                Cout[row * 256 + col] = f2bf(acc[p][r][rr]);
            }
}

// ---------------- K3: gathered MFMA GEMM, 64x64 tile, out f32 ---------------
// A = gathered A2 rows [n][c] (M=8192,K=256), B^T = f2b [k][c] (N=768)
__global__ __launch_bounds__(256) void k3_gemm(const unsigned short* __restrict__ A2,
                                               const unsigned short* __restrict__ f2b,
                                               const int* __restrict__ ids,
                                               float* __restrict__ out) {
    const int n0 = blockIdx.x * 64;
    const int k0 = blockIdx.y * 64;

    __shared__ int ids_s[64];
    __shared__ unsigned short As[64 * 32];
    __shared__ unsigned short Bs[64 * 32];

    const int tid = threadIdx.x;
    if (tid < 64) ids_s[tid] = ids[n0 + tid];
    __syncthreads();

    const int lane = tid & 63, wave = tid >> 6;
    const int wm = (wave >> 1) * 32, wn = (wave & 1) * 32;
    const int l16 = lane & 15, q = lane >> 4;

    const int r0 = tid >> 2, o0 = (tid & 3) * 8;
    const size_t ga = (size_t)ids_s[r0] * 256;       // gathered A row base
    unsigned short* AsW = &As[wave * 512];
    unsigned short* BsW = &Bs[wave * 512];

    floatx4 acc[2][2];
#pragma unroll
    for (int p = 0; p < 2; ++p)
#pragma unroll
        for (int r = 0; r < 2; ++r) acc[p][r] = (floatx4)0.f;

    for (int kk = 0; kk < C_DIM; kk += 32) {
        gl2lds16(&A2[ga + kk + o0], AsW);
        gl2lds16(&f2b[(k0 + r0) * 256 + kk + o0], BsW);
        __syncthreads();
        short8 af[2], bf[2];
#pragma unroll
        for (int p = 0; p < 2; ++p) af[p] = *(const short8*)&As[(wm + p * 16 + l16) * 32 + q * 8];
#pragma unroll
        for (int r = 0; r < 2; ++r) bf[r] = *(const short8*)&Bs[(wn + r * 16 + l16) * 32 + q * 8];
#pragma unroll
        for (int p = 0; p < 2; ++p)
#pragma unroll
            for (int r = 0; r < 2; ++r)
                acc[p][r] = __builtin_amdgcn_mfma_f32_16x16x32_bf16(af[p], bf[r], acc[p][r], 0, 0, 0);
        __syncthreads();
    }
#pragma unroll
    for (int p = 0; p < 2; ++p)
#pragma unroll
        for (int r = 0; r < 2; ++r)
#pragma unroll
            for (int rr = 0; rr < 4; ++rr) {
                const int row = n0 + wm + p * 16 + q * 4 + rr;
                const int col = k0 + wn + r * 16 + l16;
                out[(size_t)row * HID + col] = acc[p][r][rr];
            }
}

extern "C" void kernel_launch(void* const* d_in, const int* in_sizes, int n_in,
                              void* d_out, int out_size, void* d_ws, size_t ws_size,
                              hipStream_t stream) {
    // inputs: 0=x(unused), 1=ids, 2=core, 3=f0, 4=f1, 5=f2
    const int*   ids  = (const int*)d_in[1];
    const float* core = (const float*)d_in[2];
    const float* f0   = (const float*)d_in[3];
    const float* f1   = (const float*)d_in[4];
    const float* f2   = (const float*)d_in[5];
    float* out = (float*)d_out;

    char* ws = (char*)d_ws;
    unsigned short* A1t = (unsigned short*)ws;                 //  5,242,880 B
    unsigned short* A2  = (unsigned short*)(ws + 5242880);     // 15,728,640 B
    unsigned short* f1b = (unsigned short*)(ws + 20971520);    //    393,216 B
    unsigned short* f2b = (unsigned short*)(ws + 21364736);    //    393,216 B

    k01_fused<<<896, 256, 0, stream>>>(core, f0, f1, f2, A1t, f1b, f2b);
    k2_gemm<<<dim3(12, 4, A_DIM), 256, 0, stream>>>(f1b, A1t, A2);
    k3_gemm<<<dim3(128, 12), 256, 0, stream>>>(A2, f2b, ids, out);
}